// Round 8
// baseline (230.985 us; speedup 1.0000x reference)
//
#include <hip/hip_runtime.h>
#include <hip/hip_bf16.h>

#define H_   8
#define Q_   1024
#define N_   8192
#define NC_  1024
#define D_   128

// ---- converted-KV chunk geometry (32 keys per chunk) ----
#define KSTR   272                     // K row stride (16 slots + pad -> spread)
#define VOFF2  8704                    // 32*KSTR
#define VSTR2  64                      // V^T row stride (4 slots)
#define CHB2   16896                   // VOFF2 + 128*64   (= 1056 16B slots)
#define NCHT2  2048                    // teacher chunks: 8h * 256
#define NCHC2  256                     // compressed chunks: 8h * 32
#define O_OFF2 ((size_t)(NCHT2 + NCHC2) * CHB2)          // 38,928,384

typedef __attribute__((ext_vector_type(8))) short          bf16x8;
typedef __attribute__((ext_vector_type(8))) unsigned short u16x8;
typedef __attribute__((ext_vector_type(4))) float          f32x4;
typedef __attribute__((ext_vector_type(4))) unsigned int   u32x4;

__device__ __forceinline__ unsigned short f2b(float x) {
    __hip_bfloat16 h = __float2bfloat16(x);   // RNE
    unsigned short u;
    __builtin_memcpy(&u, &h, sizeof(u));
    return u;
}
__device__ __forceinline__ float b2f(unsigned short u) {
    unsigned int x = ((unsigned int)u) << 16;
    float f;
    __builtin_memcpy(&f, &x, sizeof(f));
    return f;
}
__device__ __forceinline__ void async16(void* lds, const void* gsrc) {
    __builtin_amdgcn_global_load_lds(
        (const __attribute__((address_space(1))) unsigned int*)gsrc,
        (__attribute__((address_space(3))) unsigned int*)lds, 16, 0, 0);
}

// ============================================================================
// Convert: fp32 K/V -> bf16 32-key chunks (unchanged from R7 audit: coalesced).
// ============================================================================
__global__ __launch_bounds__(256) void convert_kv(
    const float* __restrict__ Km, const float* __restrict__ Vm,
    const float* __restrict__ CKm, const float* __restrict__ CVm,
    char* __restrict__ ws)
{
    __shared__ float vl[32 * 129];
    const int cid = blockIdx.x;        // 0..2303
    const int tid = threadIdx.x;

    const float* Kp; const float* Vp; int h, kc, n;
    if (cid < NCHT2) { h = cid >> 8; kc = cid & 255; Kp = Km; Vp = Vm; n = N_; }
    else { int c2 = cid - NCHT2; h = c2 >> 5; kc = c2 & 31; Kp = CKm; Vp = CVm; n = NC_; }
    const size_t base = ((size_t)h * n + (size_t)kc * 32) * D_;

    // phase 1: V[32][128] fp32 -> LDS (coalesced)
    const float4* Vg = (const float4*)(Vp + base);
    #pragma unroll
    for (int s = 0; s < 4; ++s) {
        int fi = s * 256 + tid;                 // 0..1023
        int key = fi >> 5, dp = (fi & 31) * 4;
        float4 v = Vg[fi];
        float* d = vl + key * 129 + dp;
        d[0] = v.x; d[1] = v.y; d[2] = v.z; d[3] = v.w;
    }
    __syncthreads();

    char* cb = ws + (size_t)cid * CHB2;

    // phase 2: K 32 rows x 16 slots (512 slots)
    #pragma unroll
    for (int i = 0; i < 2; ++i) {
        int s = i * 256 + tid, r = s >> 4, sl = s & 15;
        const float4* src = (const float4*)(Kp + base + (size_t)r * D_ + sl * 8);
        float4 a = src[0], b = src[1];
        u16x8 u;
        u[0] = f2b(a.x); u[1] = f2b(a.y); u[2] = f2b(a.z); u[3] = f2b(a.w);
        u[4] = f2b(b.x); u[5] = f2b(b.y); u[6] = f2b(b.z); u[7] = f2b(b.w);
        *(u16x8*)(cb + r * KSTR + sl * 16) = u;
    }
    // phase 3: V^T 128 rows x 4 slots (512 slots)
    #pragma unroll
    for (int i = 0; i < 2; ++i) {
        int s = i * 256 + tid, r = s >> 2, sl = s & 3;   // r = d'
        const float* col = vl + (sl * 8) * 129 + r;
        u16x8 u;
        #pragma unroll
        for (int k = 0; k < 8; ++k) u[k] = f2b(col[k * 129]);
        *(u16x8*)(cb + VOFF2 + r * VSTR2 + sl * 16) = u;
    }
}

// ============================================================================
// Attention partials: 8 waves x 32 q-rows, KVB=32, dbuf 33.8KB LDS ->
// 2 blocks/CU. P never touches LDS: bpermute redistribution (EXEC-SAFE:
// all bpermutes unconditional at full wave, then cndmask-select).
// ============================================================================
template<int LOG2NG>
__global__ __launch_bounds__(512, 4) void attn_partial2(
    const float* __restrict__ Qm, char* __restrict__ ws)
{
    constexpr int NG  = 1 << LOG2NG;
    constexpr int TCH = 256 >> LOG2NG;      // teacher chunks per group
    constexpr int CCH = 32  >> LOG2NG;      // compressed chunks per group
    const size_t ML_OFF2 = O_OFF2 + (size_t)NG * 4194304;

    __shared__ __align__(16) char kvbuf[2][CHB2];      // 33,792 B

    const int tid = threadIdx.x;
    const int wq = tid >> 6, ln = tid & 63, g = ln >> 4, c = ln & 15;

    const int bid = blockIdx.x;
    const int h = bid & 7;                             // head == XCD
    const int r2 = bid >> 3;
    const int gch = r2 & (NG - 1), qt = r2 >> LOG2NG;

    // ---- Q fragments (scale folded); B-frag: lane (g,c) = Q[c+16rt][8g+i+32dc]
    bf16x8 qf[2][4];
    {
        const float scale = 0.08838834764831845f;      // 1/sqrt(128)
        #pragma unroll
        for (int rt = 0; rt < 2; ++rt) {
            const float* qrow = Qm + ((size_t)h * Q_ + qt * 256 + wq * 32 + rt * 16 + c) * D_;
            #pragma unroll
            for (int dc = 0; dc < 4; ++dc) {
                const float4* p = (const float4*)(qrow + dc * 32 + g * 8);
                float4 a = p[0], b = p[1];
                u16x8 u;
                u[0] = f2b(a.x * scale); u[1] = f2b(a.y * scale);
                u[2] = f2b(a.z * scale); u[3] = f2b(a.w * scale);
                u[4] = f2b(b.x * scale); u[5] = f2b(b.y * scale);
                u[6] = f2b(b.z * scale); u[7] = f2b(b.w * scale);
                qf[rt][dc] = __builtin_bit_cast(bf16x8, u);
            }
        }
    }

    // bpermute source byte-addresses (lane*4), fixed per thread:
    // dest word i2 pulls from lane (2*(g&1) + (i2>>1))*16 + c
    const int a_lo = ((((ln >> 4) & 1) * 2) * 16 + c) << 2;
    const int a_hi = a_lo + 64;
    const bool gl2 = (ln < 32);     // g in {0,1} -> kt=0 values, else kt=1

    auto stage = [&](size_t cid, int buf) {            // 1056 linear 16B slots
        const char* s = ws + cid * CHB2;
        char* d = kvbuf[buf];
        #pragma unroll
        for (int k = 0; k < 2; ++k)
            async16(d + (k * 512 + tid) * 16, s + (size_t)(k * 512 + tid) * 16);
        if (tid < 32) async16(d + (1024 + tid) * 16, s + (size_t)(1024 + tid) * 16);
    };

    f32x4 o[2][8];     // O[qrow=rt*16+4g+j][d=dt*16+c]
    float m[2], l[2];  // score layout: row = rt*16+c

    auto compute = [&](int cur) {
        const char* Kc = kvbuf[cur];
        const char* Vc = kvbuf[cur] + VOFF2;

        // ---- S^T = K Q^T : lane (g,c) -> S[key=16kt+4g+j][q=rt*16+c]
        f32x4 s[2][2];
        #pragma unroll
        for (int kt = 0; kt < 2; ++kt)
            #pragma unroll
            for (int rt = 0; rt < 2; ++rt) s[kt][rt] = (f32x4){0.f, 0.f, 0.f, 0.f};
        __builtin_amdgcn_s_setprio(1);
        #pragma unroll
        for (int dc = 0; dc < 4; ++dc) {
            #pragma unroll
            for (int kt = 0; kt < 2; ++kt) {
                bf16x8 kf = *(const bf16x8*)(Kc + (kt * 16 + c) * KSTR + dc * 64 + g * 16);
                s[kt][0] = __builtin_amdgcn_mfma_f32_16x16x32_bf16(kf, qf[0][dc], s[kt][0], 0, 0, 0);
                s[kt][1] = __builtin_amdgcn_mfma_f32_16x16x32_bf16(kf, qf[1][dc], s[kt][1], 0, 0, 0);
            }
        }
        __builtin_amdgcn_s_setprio(0);
        // ---- row max ----
        float mx[2];
        #pragma unroll
        for (int rt = 0; rt < 2; ++rt) {
            float a = fmaxf(fmaxf(s[0][rt][0], s[0][rt][1]), fmaxf(s[0][rt][2], s[0][rt][3]));
            float b = fmaxf(fmaxf(s[1][rt][0], s[1][rt][1]), fmaxf(s[1][rt][2], s[1][rt][3]));
            mx[rt] = fmaxf(a, b);
            mx[rt] = fmaxf(mx[rt], __shfl_xor(mx[rt], 16));
            mx[rt] = fmaxf(mx[rt], __shfl_xor(mx[rt], 32));
        }
        // ---- defer-max rescale (rare; wave-uniform branch -> full exec) ----
        int need = (mx[0] > m[0] + 8.f) | (mx[1] > m[1] + 8.f);
        if (__any(need)) {
            #pragma unroll
            for (int rt = 0; rt < 2; ++rt) {
                float mn = fmaxf(m[rt], mx[rt]);
                float al = __expf(m[rt] - mn);
                l[rt] *= al; m[rt] = mn;
                int ia = __builtin_bit_cast(int, al);
                #pragma unroll
                for (int j = 0; j < 4; ++j) {   // alpha of o-row rt*16+4g+j
                    int srcl = (ln & 48) + ((ln >> 2) & 12) + j;
                    float aj = __builtin_bit_cast(float,
                        __builtin_amdgcn_ds_bpermute(srcl << 2, ia));
                    #pragma unroll
                    for (int dt = 0; dt < 8; ++dt) o[rt][dt][j] *= aj;
                }
            }
        }
        // ---- P = exp(S-m); pack + EXEC-SAFE bpermute into PV A-frag ----
        bf16x8 pa[2];
        #pragma unroll
        for (int rt = 0; rt < 2; ++rt) {
            float p00 = __expf(s[0][rt][0] - m[rt]), p01 = __expf(s[0][rt][1] - m[rt]);
            float p02 = __expf(s[0][rt][2] - m[rt]), p03 = __expf(s[0][rt][3] - m[rt]);
            float p10 = __expf(s[1][rt][0] - m[rt]), p11 = __expf(s[1][rt][1] - m[rt]);
            float p12 = __expf(s[1][rt][2] - m[rt]), p13 = __expf(s[1][rt][3] - m[rt]);
            l[rt] += ((p00 + p01) + (p02 + p03)) + ((p10 + p11) + (p12 + p13));
            int v00 = (int)((unsigned)f2b(p00) | ((unsigned)f2b(p01) << 16));
            int v01 = (int)((unsigned)f2b(p02) | ((unsigned)f2b(p03) << 16));
            int v10 = (int)((unsigned)f2b(p10) | ((unsigned)f2b(p11) << 16));
            int v11 = (int)((unsigned)f2b(p12) | ((unsigned)f2b(p13) << 16));
            // ALL bpermutes unconditional (full-wave exec), select after.
            int b00 = __builtin_amdgcn_ds_bpermute(a_lo, v00);
            int b01 = __builtin_amdgcn_ds_bpermute(a_lo, v01);
            int b02 = __builtin_amdgcn_ds_bpermute(a_hi, v00);
            int b03 = __builtin_amdgcn_ds_bpermute(a_hi, v01);
            int b10 = __builtin_amdgcn_ds_bpermute(a_lo, v10);
            int b11 = __builtin_amdgcn_ds_bpermute(a_lo, v11);
            int b12 = __builtin_amdgcn_ds_bpermute(a_hi, v10);
            int b13 = __builtin_amdgcn_ds_bpermute(a_hi, v11);
            u32x4 w;
            w[0] = (unsigned)(gl2 ? b00 : b10);
            w[1] = (unsigned)(gl2 ? b01 : b11);
            w[2] = (unsigned)(gl2 ? b02 : b12);
            w[3] = (unsigned)(gl2 ? b03 : b13);
            pa[rt] = __builtin_bit_cast(bf16x8, w);
        }
        // ---- PV : A = P[qrow][keys 8g+i], B = V^T ----
        __builtin_amdgcn_s_setprio(1);
        #pragma unroll
        for (int dt = 0; dt < 8; ++dt) {
            bf16x8 vf = *(const bf16x8*)(Vc + (dt * 16 + c) * VSTR2 + g * 16);
            o[0][dt] = __builtin_amdgcn_mfma_f32_16x16x32_bf16(pa[0], vf, o[0][dt], 0, 0, 0);
            o[1][dt] = __builtin_amdgcn_mfma_f32_16x16x32_bf16(pa[1], vf, o[1][dt], 0, 0, 0);
        }
        __builtin_amdgcn_s_setprio(0);
    };

    // iter t: syncthreads (drains stage(t)) -> issue stage(t+1) -> compute(t)
    auto run_pass = [&](size_t cbase, int niter) {
        #pragma unroll
        for (int rt = 0; rt < 2; ++rt) {
            #pragma unroll
            for (int dt = 0; dt < 8; ++dt) o[rt][dt] = (f32x4){0.f, 0.f, 0.f, 0.f};
            m[rt] = -1e30f; l[rt] = 0.f;
        }
        stage(cbase, 0);
        for (int t = 0; t < niter; ++t) {
            __syncthreads();                      // drains stage(t); buf(t) ready
            if (t + 1 < niter) stage(cbase + t + 1, (t + 1) & 1);
            compute(t & 1);
        }
        #pragma unroll
        for (int rt = 0; rt < 2; ++rt) {          // row-sum across the 4 g-lanes
            l[rt] += __shfl_xor(l[rt], 16);
            l[rt] += __shfl_xor(l[rt], 32);
        }
    };

    auto store_partials = [&](int a) {
        unsigned short* oP = (unsigned short*)(ws + O_OFF2);
        float2* mlP = (float2*)(ws + ML_OFF2);
        #pragma unroll
        for (int rt = 0; rt < 2; ++rt)
            #pragma unroll
            for (int j = 0; j < 4; ++j) {
                int row_glob = h * 1024 + qt * 256 + wq * 32 + rt * 16 + 4 * g + j;
                size_t rec = ((size_t)row_glob * 2 + a) * NG + gch;
                unsigned short* dst = oP + rec * 128 + c;
                #pragma unroll
                for (int dt = 0; dt < 8; ++dt) dst[dt * 16] = f2b(o[rt][dt][j]);
            }
        if (g == 0) {
            #pragma unroll
            for (int rt = 0; rt < 2; ++rt) {
                int row_glob = h * 1024 + qt * 256 + wq * 32 + rt * 16 + c;
                size_t rec = ((size_t)row_glob * 2 + a) * NG + gch;
                mlP[rec] = make_float2(m[rt], l[rt]);
            }
        }
    };

    run_pass((size_t)h * 256 + gch * TCH, TCH);            // teacher
    store_partials(0);
    run_pass((size_t)NCHT2 + h * 32 + gch * CCH, CCH);     // compressed
    store_partials(1);
}

// ============================================================================
// Combine split-K partials (global softmax) for both attentions + fused MSE.
// ============================================================================
template<int LOG2NG>
__global__ __launch_bounds__(256) void combine_mse(
    const char* __restrict__ ws, float* __restrict__ out)
{
    constexpr int NG = 1 << LOG2NG;
    const size_t ML_OFF2 = O_OFF2 + (size_t)NG * 4194304;
    __shared__ float red[4];
    const int tid = threadIdx.x;
    const int row = blockIdx.x * 32 + (tid >> 3);
    const int p   = tid & 7;
    const unsigned short* oP = (const unsigned short*)(ws + O_OFF2);
    const float2* mlP = (const float2*)(ws + ML_OFF2);

    float z[2][16];
    #pragma unroll
    for (int a = 0; a < 2; ++a) {
        size_t rec0 = ((size_t)row * 2 + a) * NG;
        float M = -1e30f;
        float mg[NG], lg[NG];
        #pragma unroll
        for (int g = 0; g < NG; ++g) {
            float2 t = mlP[rec0 + g];
            mg[g] = t.x; lg[g] = t.y;
            M = fmaxf(M, mg[g]);
        }
        float L = 0.f, acc[16];
        #pragma unroll
        for (int i = 0; i < 16; ++i) acc[i] = 0.f;
        #pragma unroll
        for (int g = 0; g < NG; ++g) {
            float w = __expf(mg[g] - M);
            L += w * lg[g];
            const unsigned short* op = oP + (rec0 + g) * 128 + p * 16;
            u16x8 lo = *(const u16x8*)op;
            u16x8 hi = *(const u16x8*)(op + 8);
            #pragma unroll
            for (int i = 0; i < 8; ++i) {
                acc[i]     += w * b2f(lo[i]);
                acc[8 + i] += w * b2f(hi[i]);
            }
        }
        float invL = 1.0f / L;
        #pragma unroll
        for (int i = 0; i < 16; ++i) z[a][i] = acc[i] * invL;
    }
    float sq = 0.f;
    #pragma unroll
    for (int i = 0; i < 16; ++i) { float d = z[0][i] - z[1][i]; sq += d * d; }
    #pragma unroll
    for (int off = 1; off < 64; off <<= 1) sq += __shfl_xor(sq, off);
    if ((tid & 63) == 0) red[tid >> 6] = sq;
    __syncthreads();
    if (tid == 0)
        atomicAdd(out, (red[0] + red[1] + red[2] + red[3]) * (1.0f / 1048576.0f));
}

extern "C" void kernel_launch(void* const* d_in, const int* in_sizes, int n_in,
                              void* d_out, int out_size, void* d_ws, size_t ws_size,
                              hipStream_t stream) {
    const float* q  = (const float*)d_in[0];
    const float* k  = (const float*)d_in[1];
    const float* v  = (const float*)d_in[2];
    const float* ck = (const float*)d_in[3];
    const float* cv = (const float*)d_in[4];
    float* out = (float*)d_out;
    char* ws = (char*)d_ws;

    hipMemsetAsync(out, 0, sizeof(float), stream);

    const size_t NEED_A = O_OFF2 + (size_t)16 * 4194304 + (size_t)8192 * 2 * 16 * 8; // 108,134,400
    // NEED_B = O_OFF2 + 8*4194304 + 8192*2*8*8 = 73,531,392

    convert_kv<<<dim3(NCHT2 + NCHC2), dim3(256), 0, stream>>>(k, v, ck, cv, ws);
    if (ws_size >= NEED_A) {
        attn_partial2<4><<<dim3(512), dim3(512), 0, stream>>>(q, ws);
        combine_mse<4><<<dim3(256), dim3(256), 0, stream>>>(ws, out);
    } else {
        attn_partial2<3><<<dim3(256), dim3(512), 0, stream>>>(q, ws);
        combine_mse<3><<<dim3(256), dim3(256), 0, stream>>>(ws, out);
    }
}